// Round 3
// baseline (122.201 us; speedup 1.0000x reference)
//
#include <hip/hip_runtime.h>

typedef _Float16 f16x8 __attribute__((ext_vector_type(8)));
typedef float f32x4 __attribute__((ext_vector_type(4)));

#define MDIM 64000
#define KDIM 512
#define NCOLS 514
#define NPAD 640
#define BM 128
#define BN 128
#define BK 64
#define KT (KDIM / BK)  // 8
#define NT 5            // N tiles
#define NWG 2500

// global -> LDS direct DMA, 16B per lane, LDS dest = wave-uniform base + lane*16
#define GLOAD_LDS16(g, l)                                        \
  __builtin_amdgcn_global_load_lds(                              \
      (const __attribute__((address_space(1))) void*)(g),        \
      (__attribute__((address_space(3))) void*)(l), 16, 0, 0)

// Build interleaved f16 weight matrix Wb[n][k], n in [0,640):
//   n even -> real_kernel[n/2], n odd -> imag_kernel[n/2], n>=514 -> 0
__global__ void prep_w(const float* __restrict__ rk, const float* __restrict__ ik,
                       _Float16* __restrict__ wb) {
  int n = blockIdx.x;
  int k = threadIdx.x;
  float v = 0.0f;
  if (n < NCOLS) {
    int bin = n >> 1;
    const float* src = (n & 1) ? ik : rk;
    v = src[bin * KDIM + k];
  }
  wb[(size_t)n * KDIM + k] = (_Float16)v;
}

__global__ __launch_bounds__(256, 2)
void dft_gemm(const float* __restrict__ x, const _Float16* __restrict__ wb,
              float* __restrict__ out) {
  // Double-buffered f16 tiles, 16 KB each buffer per operand (64 KB total).
  // Chunk-swizzled: logical 16B-chunk c of row r lives at physical c^(r&7).
  __shared__ _Float16 As[2][BM * BK];
  __shared__ _Float16 Bs[2][BN * BK];

  const int tid = threadIdx.x;
  const int l   = tid & 63;
  const int w   = tid >> 6;
  const int lr  = l & 15;   // fragment row/col lane index
  const int lg  = l >> 4;   // lane k-group 0..3
  const int wm  = (w >> 1) * 64;
  const int wn  = (w & 1) * 64;

  // T1: bijective chunked XCD swizzle (m204). Consecutive wgid -> same XCD,
  // so the 5 N-tile blocks of one M-tile share the x slab in one L2.
  const int xcd = blockIdx.x & 7;
  const int lid = blockIdx.x >> 3;
  const int q   = NWG >> 3;          // 312
  const int r   = NWG & 7;           // 4
  const int wgid = (xcd < r) ? xcd * (q + 1) + lid
                             : r * (q + 1) + (xcd - r) * q + lid;
  const int mt = wgid / NT;
  const int nt = wgid - mt * NT;
  const int m0 = mt * BM;
  const int n0 = nt * BN;

  f32x4 acc[4][4] = {};

  // A staging: thread owns row arow = tid>>1, f32 cols acol..acol+31
  const int arow = tid >> 1;
  const int acol = (tid & 1) * 32;
  const float* aptr = x + (size_t)(m0 + arow) * KDIM + acol;

  // B staging lane decomposition (global_load_lds, source pre-swizzled)
  const int brl = l >> 3;  // row-within-issue 0..7
  const int bcp = l & 7;   // phys 16B chunk 0..7

  f32x4 areg[8];  // in-flight A tile (32 f32), statically indexed

#define ISSUE_A(t)                                                        \
  {                                                                       \
    _Pragma("unroll")                                                     \
    for (int j = 0; j < 8; ++j)                                           \
      areg[j] = *reinterpret_cast<const f32x4*>(aptr + (t) * BK + j * 4); \
  }

#define WRITE_A(buf)                                                      \
  {                                                                       \
    _Pragma("unroll")                                                     \
    for (int c = 0; c < 4; ++c) {                                         \
      f16x8 h;                                                            \
      _Pragma("unroll")                                                   \
      for (int e = 0; e < 4; ++e) {                                       \
        h[e]     = (_Float16)areg[c * 2][e];                              \
        h[e + 4] = (_Float16)areg[c * 2 + 1][e];                          \
      }                                                                   \
      int pc = ((tid & 1) * 4 + c) ^ (arow & 7);                          \
      *reinterpret_cast<f16x8*>(&As[buf][arow * BK + pc * 8]) = h;        \
    }                                                                     \
  }

#define ISSUE_B(t, buf)                                                   \
  {                                                                       \
    _Pragma("unroll")                                                     \
    for (int s = 0; s < 4; ++s) {                                         \
      int r0  = w * 32 + s * 8;                                           \
      int row = r0 + brl;                                                 \
      int cl  = bcp ^ (row & 7);                                          \
      const _Float16* g =                                                 \
          wb + (size_t)(n0 + row) * KDIM + (t) * BK + cl * 8;             \
      GLOAD_LDS16(g, &Bs[buf][r0 * BK]);                                  \
    }                                                                     \
  }

#define COMPUTE(buf)                                                      \
  {                                                                       \
    _Pragma("unroll")                                                     \
    for (int ks = 0; ks < 2; ++ks) {                                      \
      f16x8 av[4], bv[4];                                                 \
      _Pragma("unroll")                                                   \
      for (int fm = 0; fm < 4; ++fm) {                                    \
        int row = wm + fm * 16 + lr;                                      \
        int c   = (ks * 4 + lg) ^ (row & 7);                              \
        av[fm] = *reinterpret_cast<const f16x8*>(&As[buf][row * BK + c * 8]); \
      }                                                                   \
      _Pragma("unroll")                                                   \
      for (int fn = 0; fn < 4; ++fn) {                                    \
        int row = wn + fn * 16 + lr;                                      \
        int c   = (ks * 4 + lg) ^ (row & 7);                              \
        bv[fn] = *reinterpret_cast<const f16x8*>(&Bs[buf][row * BK + c * 8]); \
      }                                                                   \
      _Pragma("unroll")                                                   \
      for (int fm = 0; fm < 4; ++fm)                                      \
        _Pragma("unroll")                                                 \
        for (int fn = 0; fn < 4; ++fn)                                    \
          acc[fm][fn] = __builtin_amdgcn_mfma_f32_16x16x32_f16(           \
              av[fm], bv[fn], acc[fm][fn], 0, 0, 0);                      \
    }                                                                     \
  }

  // ---- prologue: stage tile 0 into buffer 0 ----
  ISSUE_B(0, 0);
  ISSUE_A(0);
  WRITE_A(0);       // compiler inserts vmcnt wait for areg deps
  __syncthreads();  // implicit vmcnt(0) drain covers B DMA

  // ---- 2-phase pipelined K loop: stage t+1 under compute t ----
  int cur = 0;
  for (int t = 0; t < KT; ++t) {
    if (t + 1 < KT) {
      ISSUE_B(t + 1, cur ^ 1);
      ISSUE_A(t + 1);
    }
    COMPUTE(cur);
    if (t + 1 < KT) {
      WRITE_A(cur ^ 1);
      __syncthreads();  // drains B DMA + A ds_writes for t+1
    }
    cur ^= 1;
  }

  // ---- epilogue: C/D layout col=lane&15, row=(lane>>4)*4+reg ----
#pragma unroll
  for (int fm = 0; fm < 4; ++fm) {
#pragma unroll
    for (int rr = 0; rr < 4; ++rr) {
      int row = m0 + wm + fm * 16 + lg * 4 + rr;
      size_t base = (size_t)row * NCOLS;
#pragma unroll
      for (int fn = 0; fn < 4; ++fn) {
        int col = n0 + wn + fn * 16 + lr;
        if (col < NCOLS) out[base + col] = acc[fm][fn][rr];
      }
    }
  }
#undef ISSUE_A
#undef WRITE_A
#undef ISSUE_B
#undef COMPUTE
}

extern "C" void kernel_launch(void* const* d_in, const int* in_sizes, int n_in,
                              void* d_out, int out_size, void* d_ws, size_t ws_size,
                              hipStream_t stream) {
  const float* x  = (const float*)d_in[0];
  const float* rk = (const float*)d_in[1];
  const float* ik = (const float*)d_in[2];
  float* out = (float*)d_out;
  _Float16* wb = (_Float16*)d_ws;  // 640*512*2 B = 655 KB scratch

  prep_w<<<dim3(NPAD), dim3(KDIM), 0, stream>>>(rk, ik, wb);

  dim3 grid(NWG);  // 500 M-tiles x 5 N-tiles, M-major via chunked XCD swizzle
  dft_gemm<<<grid, dim3(256), 0, stream>>>(x, wb, out);
}

// Round 5
// 114.002 us; speedup vs baseline: 1.0719x; 1.0719x over previous
//
#include <hip/hip_runtime.h>

typedef _Float16 f16x8 __attribute__((ext_vector_type(8)));
typedef float f32x4 __attribute__((ext_vector_type(4)));

#define MDIM 64000
#define KDIM 512
#define NCOLS 514
#define NPAD 512
#define BM 128
#define BN 128
#define BK 64
#define KT (KDIM / BK)  // 8
#define NT 4            // N tiles (cols 0..511); Nyquist cols 512/513 analytic
#define NWG 2000        // 500 M-tiles x 4 N-tiles, divisible by 8

// global -> LDS direct DMA, 16B per lane, LDS dest = wave-uniform base + lane*16
#define GLOAD_LDS16(g, l)                                        \
  __builtin_amdgcn_global_load_lds(                              \
      (const __attribute__((address_space(1))) void*)(g),        \
      (__attribute__((address_space(3))) void*)(l), 16, 0, 0)

// Build interleaved f16 weight matrix Wb[n][k], n in [0,512):
//   n even -> real_kernel[n/2], n odd -> imag_kernel[n/2]
__global__ void prep_w(const float* __restrict__ rk, const float* __restrict__ ik,
                       _Float16* __restrict__ wb) {
  int n = blockIdx.x;
  int k = threadIdx.x;
  int bin = n >> 1;
  const float* src = (n & 1) ? ik : rk;
  wb[(size_t)n * KDIM + k] = (_Float16)src[bin * KDIM + k];
}

__global__ __launch_bounds__(256, 3)
void dft_gemm(const float* __restrict__ x, const _Float16* __restrict__ wb,
              float* __restrict__ out) {
  // A single-buffered f16 (reg-staged), B double-buffered via global_load_lds.
  // Chunk-swizzled: logical 16B-chunk c of row r lives at physical c^(r&7).
  __shared__ _Float16 As[BM * BK];     // 16 KB
  __shared__ _Float16 Bs[2][BN * BK];  // 32 KB  -> 48 KB total, 3 blocks/CU

  const int tid = threadIdx.x;
  const int l   = tid & 63;
  const int w   = tid >> 6;
  const int lr  = l & 15;   // fragment row/col lane index
  const int lg  = l >> 4;   // lane k-group 0..3
  const int wm  = (w >> 1) * 64;
  const int wn  = (w & 1) * 64;

  // T1: XCD swizzle (NWG % 8 == 0 -> simple chunked bijection). Consecutive
  // wgid -> same XCD, so the 4 N-tile blocks of one M-tile share x in one L2.
  const int wgid = (blockIdx.x & 7) * (NWG / 8) + (blockIdx.x >> 3);
  const int mt = wgid >> 2;
  const int nt = wgid & 3;
  const int m0 = mt * BM;
  const int n0 = nt * BN;

  f32x4 acc[4][4] = {};
  float nyq = 0.0f;  // alternating-sum accumulator (Nyquist bin), nt==0 only

  // A staging: thread owns row arow = tid>>1, f32 cols acol..acol+31
  const int arow = tid >> 1;
  const int acol = (tid & 1) * 32;
  const float* aptr = x + (size_t)(m0 + arow) * KDIM + acol;

  // B staging lane decomposition (global_load_lds, source pre-swizzled)
  const int brl = l >> 3;  // row-within-issue 0..7
  const int bcp = l & 7;   // phys 16B chunk 0..7

  f32x4 areg[8];  // in-flight A tile (32 f32), statically indexed

#define ISSUE_A(t)                                                        \
  {                                                                       \
    _Pragma("unroll")                                                     \
    for (int j = 0; j < 8; ++j)                                           \
      areg[j] = *reinterpret_cast<const f32x4*>(aptr + (t) * BK + j * 4); \
  }

#define WRITE_A()                                                         \
  {                                                                       \
    _Pragma("unroll")                                                     \
    for (int c = 0; c < 4; ++c) {                                         \
      f16x8 h;                                                            \
      _Pragma("unroll")                                                   \
      for (int e = 0; e < 4; ++e) {                                       \
        h[e]     = (_Float16)areg[c * 2][e];                              \
        h[e + 4] = (_Float16)areg[c * 2 + 1][e];                          \
      }                                                                   \
      int pc = ((tid & 1) * 4 + c) ^ (arow & 7);                          \
      *reinterpret_cast<f16x8*>(&As[arow * BK + pc * 8]) = h;             \
    }                                                                     \
  }

// Nyquist: sign = (-1)^(global col); k starts even per areg chunk
#define NYQ()                                                             \
  {                                                                       \
    _Pragma("unroll")                                                     \
    for (int j = 0; j < 8; ++j)                                           \
      nyq += (areg[j][0] - areg[j][1]) + (areg[j][2] - areg[j][3]);       \
  }

#define ISSUE_B(t, buf)                                                   \
  {                                                                       \
    _Pragma("unroll")                                                     \
    for (int s = 0; s < 4; ++s) {                                         \
      int r0  = w * 32 + s * 8;                                           \
      int row = r0 + brl;                                                 \
      int cl  = bcp ^ (row & 7);                                          \
      const _Float16* g =                                                 \
          wb + (size_t)(n0 + row) * KDIM + (t) * BK + cl * 8;             \
      GLOAD_LDS16(g, &Bs[buf][r0 * BK]);                                  \
    }                                                                     \
  }

#define COMPUTE(buf)                                                      \
  {                                                                       \
    _Pragma("unroll")                                                     \
    for (int ks = 0; ks < 2; ++ks) {                                      \
      f16x8 av[4], bv[4];                                                 \
      _Pragma("unroll")                                                   \
      for (int fm = 0; fm < 4; ++fm) {                                    \
        int row = wm + fm * 16 + lr;                                      \
        int c   = (ks * 4 + lg) ^ (row & 7);                              \
        av[fm] = *reinterpret_cast<const f16x8*>(&As[row * BK + c * 8]);  \
      }                                                                   \
      _Pragma("unroll")                                                   \
      for (int fn = 0; fn < 4; ++fn) {                                    \
        int row = wn + fn * 16 + lr;                                      \
        int c   = (ks * 4 + lg) ^ (row & 7);                              \
        bv[fn] = *reinterpret_cast<const f16x8*>(&Bs[buf][row * BK + c * 8]); \
      }                                                                   \
      _Pragma("unroll")                                                   \
      for (int fm = 0; fm < 4; ++fm)                                      \
        _Pragma("unroll")                                                 \
        for (int fn = 0; fn < 4; ++fn)                                    \
          acc[fm][fn] = __builtin_amdgcn_mfma_f32_16x16x32_f16(           \
              av[fm], bv[fn], acc[fm][fn], 0, 0, 0);                      \
    }                                                                     \
  }

  // ---- prologue: stage tile 0 ----
  ISSUE_A(0);
  ISSUE_B(0, 0);
  WRITE_A();  // vmcnt wait for areg; B DMA drains at the syncthreads
  if (nt == 0) NYQ();
  __syncthreads();

  // ---- pipelined K loop: global loads for t+1 in flight under COMPUTE(t) ----
  int b = 0;
  for (int t = 0; t < KT; ++t) {
    if (t + 1 < KT) {
      ISSUE_A(t + 1);         // older vmem: regs
      ISSUE_B(t + 1, b ^ 1);  // newer vmem: DMA into inactive buffer
    }
    COMPUTE(b);
    if (t + 1 < KT) {
      // Race-proof barrier sequence (rule #18): no instruction may cross,
      // and this wave's LDS reads must have EXECUTED before it signals.
      __builtin_amdgcn_sched_barrier(0);
      asm volatile("s_waitcnt lgkmcnt(0)" ::: "memory");
      __builtin_amdgcn_s_barrier();
      __builtin_amdgcn_sched_barrier(0);
      WRITE_A();               // waits A-loads (vmcnt<=4); B DMA keeps flying
      if (nt == 0) NYQ();
      __syncthreads();         // drain: B DMA landed during COMPUTE
    }
    b ^= 1;
  }

  // ---- epilogue: C/D layout col=lane&15, row=(lane>>4)*4+reg ----
#pragma unroll
  for (int fm = 0; fm < 4; ++fm) {
#pragma unroll
    for (int rr = 0; rr < 4; ++rr) {
      int row = m0 + wm + fm * 16 + lg * 4 + rr;
      size_t base = (size_t)row * NCOLS;
#pragma unroll
      for (int fn = 0; fn < 4; ++fn)
        out[base + n0 + wn + fn * 16 + lr] = acc[fm][fn][rr];
    }
  }

  // ---- Nyquist bin: col 512 = alternating sum, col 513 = 0 ----
  if (nt == 0) {
    float tot = nyq + __shfl_xor(nyq, 1);
    if ((tid & 1) == 0) {
      size_t base = (size_t)(m0 + arow) * NCOLS;
      out[base + 512] = tot;
      out[base + 513] = 0.0f;
    }
  }
#undef ISSUE_A
#undef WRITE_A
#undef NYQ
#undef ISSUE_B
#undef COMPUTE
}

extern "C" void kernel_launch(void* const* d_in, const int* in_sizes, int n_in,
                              void* d_out, int out_size, void* d_ws, size_t ws_size,
                              hipStream_t stream) {
  const float* x  = (const float*)d_in[0];
  const float* rk = (const float*)d_in[1];
  const float* ik = (const float*)d_in[2];
  float* out = (float*)d_out;
  _Float16* wb = (_Float16*)d_ws;  // 512*512*2 B = 512 KB scratch

  prep_w<<<dim3(NPAD), dim3(KDIM), 0, stream>>>(rk, ik, wb);

  dim3 grid(NWG);
  dft_gemm<<<grid, dim3(256), 0, stream>>>(x, wb, out);
}

// Round 6
// 90.835 us; speedup vs baseline: 1.3453x; 1.2550x over previous
//
#include <hip/hip_runtime.h>

typedef _Float16 f16x8 __attribute__((ext_vector_type(8)));
typedef float f32x4 __attribute__((ext_vector_type(4)));

#define MDIM 64000
#define KDIM 512
#define NCOLS 514
#define NPAD 512
#define BM 128
#define BN 128
#define BK 32
#define KT (KDIM / BK)  // 16
#define NT 4            // N tiles (cols 0..511); Nyquist cols 512/513 analytic
#define NWG 2000        // 500 M-tiles x 4 N-tiles, divisible by 8

// global -> LDS direct DMA, 16B per lane, LDS dest = wave-uniform base + lane*16
#define GLOAD_LDS16(g, l)                                        \
  __builtin_amdgcn_global_load_lds(                              \
      (const __attribute__((address_space(1))) void*)(g),        \
      (__attribute__((address_space(3))) void*)(l), 16, 0, 0)

// Build interleaved f16 weight matrix Wb[n][k], n in [0,512):
//   n even -> real_kernel[n/2], n odd -> imag_kernel[n/2]
__global__ void prep_w(const float* __restrict__ rk, const float* __restrict__ ik,
                       _Float16* __restrict__ wb) {
  int n = blockIdx.x;
  int k = threadIdx.x;
  int bin = n >> 1;
  const float* src = (n & 1) ? ik : rk;
  wb[(size_t)n * KDIM + k] = (_Float16)src[bin * KDIM + k];
}

__global__ __launch_bounds__(256, 3)
void dft_gemm(const float* __restrict__ x, const _Float16* __restrict__ wb,
              float* __restrict__ out) {
  // Both operands double-buffered, staged ONLY via global_load_lds (no reg
  // round-trip -> nothing for the scheduler to sink). 48 KB -> 3 blocks/CU.
  // A chunk-swizzle: logical 16B chunk c of row r at phys c^(r&7)   (8 chunks)
  // B chunk-swizzle: logical 16B chunk c of row r at phys c^((r>>1)&3) (4 chunks)
  __shared__ float As[2][BM * BK];     // 2 x 16 KB
  __shared__ _Float16 Bs[2][BN * BK];  // 2 x  8 KB

  const int tid = threadIdx.x;
  const int l   = tid & 63;
  const int w   = tid >> 6;
  const int lr  = l & 15;   // fragment row/col lane index
  const int lg  = l >> 4;   // lane k-group 0..3
  const int wm  = (w >> 1) * 64;
  const int wn  = (w & 1) * 64;

  // T1: XCD swizzle (NWG % 8 == 0 -> simple chunked bijection). Consecutive
  // wgid -> same XCD, so the 4 N-tile blocks of one M-tile share x in one L2.
  const int wgid = (blockIdx.x & 7) * (NWG / 8) + (blockIdx.x >> 3);
  const int mt = wgid >> 2;
  const int nt = wgid & 3;
  const int m0 = mt * BM;
  const int n0 = nt * BN;

  f32x4 acc[4][4] = {};
  float nyq = 0.0f;

  // A staging (4 issues/thread): issue s covers rows w*32+s*8 .. +7.
  // lane row-in-issue = l>>3, phys chunk = l&7, logical = (l&7)^(l>>3)
  // (row&7 == l>>3 since r0 is a multiple of 8).
  const int arow0 = w * 32 + (l >> 3);
  const float* asrc = x + (size_t)(m0 + arow0) * KDIM + (((l & 7) ^ (l >> 3)) << 2);

  // B staging (2 issues/thread): issue s covers rows w*32+s*16 .. +15.
  // lane row-in-issue = l>>2, phys chunk = l&3, logical = (l&3)^((l>>3)&3)
  // ((row>>1)&3 == (l>>3)&3 since r0 is a multiple of 16).
  const int brow0 = w * 32 + (l >> 2);
  const _Float16* bsrc =
      wb + (size_t)(n0 + brow0) * KDIM + (((l & 3) ^ ((l >> 3) & 3)) << 3);

#define STAGE(t, b)                                                     \
  {                                                                     \
    _Pragma("unroll")                                                   \
    for (int s = 0; s < 4; ++s)                                         \
      GLOAD_LDS16(asrc + (size_t)s * 8 * KDIM + (t) * BK,              \
                  &As[b][(w * 32 + s * 8) * BK]);                       \
    _Pragma("unroll")                                                   \
    for (int s = 0; s < 2; ++s)                                         \
      GLOAD_LDS16(bsrc + (size_t)s * 16 * KDIM + (t) * BK,             \
                  &Bs[b][(w * 32 + s * 16) * BK]);                      \
  }

#define COMPUTE(b)                                                     \
  {                                                                    \
    f16x8 av[4], bv[4];                                                \
    _Pragma("unroll")                                                  \
    for (int fm = 0; fm < 4; ++fm) {                                   \
      int row = wm + fm * 16 + lr;                                     \
      int sw  = lr & 7; /* row&7 */                                    \
      int c0  = lg * 2;                                                \
      f32x4 lo = *reinterpret_cast<const f32x4*>(                      \
          &As[b][row * BK + ((c0 ^ sw) << 2)]);                        \
      f32x4 hi = *reinterpret_cast<const f32x4*>(                      \
          &As[b][row * BK + (((c0 + 1) ^ sw) << 2)]);                  \
      f16x8 h;                                                         \
      h[0] = (_Float16)lo[0]; h[1] = (_Float16)lo[1];                  \
      h[2] = (_Float16)lo[2]; h[3] = (_Float16)lo[3];                  \
      h[4] = (_Float16)hi[0]; h[5] = (_Float16)hi[1];                  \
      h[6] = (_Float16)hi[2]; h[7] = (_Float16)hi[3];                  \
      av[fm] = h;                                                      \
    }                                                                  \
    _Pragma("unroll")                                                  \
    for (int fn = 0; fn < 4; ++fn) {                                   \
      int row = wn + fn * 16 + lr;                                     \
      int c   = lg ^ ((lr >> 1) & 3); /* (row>>1)&3 */                 \
      bv[fn] = *reinterpret_cast<const f16x8*>(&Bs[b][row * BK + (c << 3)]); \
    }                                                                  \
    _Pragma("unroll")                                                  \
    for (int fm = 0; fm < 4; ++fm)                                     \
      _Pragma("unroll")                                                \
      for (int fn = 0; fn < 4; ++fn)                                   \
        acc[fm][fn] = __builtin_amdgcn_mfma_f32_16x16x32_f16(          \
            av[fm], bv[fn], acc[fm][fn], 0, 0, 0);                     \
  }

  // Nyquist alternating sum from the landed A tile (nt==0 blocks only).
  // Thread pair per row: row = tid>>1, 4 chunks at (tid&1)*4+j.
  const int nrow = tid >> 1;
#define NYQ(b)                                                         \
  {                                                                    \
    _Pragma("unroll")                                                  \
    for (int j = 0; j < 4; ++j) {                                      \
      int c = ((tid & 1) * 4 + j) ^ (nrow & 7);                        \
      f32x4 v = *reinterpret_cast<const f32x4*>(&As[b][nrow * BK + (c << 2)]); \
      nyq += (v[0] - v[1]) + (v[2] - v[3]);                            \
    }                                                                  \
  }

  // ---- prologue ----
  STAGE(0, 0);
  __syncthreads();

  // ---- 2-phase K loop: one barrier per iteration ----
  int b = 0;
  for (int t = 0; t < KT; ++t) {
    if (t + 1 < KT) STAGE(t + 1, b ^ 1);
    COMPUTE(b);
    if (nt == 0) NYQ(b);
    __syncthreads();  // waits own lgkm (reads done) + vmcnt (t+1 DMA landed)
    b ^= 1;
  }

  // ---- epilogue: C/D layout col=lane&15, row=(lane>>4)*4+reg ----
#pragma unroll
  for (int fm = 0; fm < 4; ++fm) {
#pragma unroll
    for (int rr = 0; rr < 4; ++rr) {
      int row = m0 + wm + fm * 16 + lg * 4 + rr;
      size_t base = (size_t)row * NCOLS;
#pragma unroll
      for (int fn = 0; fn < 4; ++fn)
        out[base + n0 + wn + fn * 16 + lr] = acc[fm][fn][rr];
    }
  }

  // ---- Nyquist bin: col 512 = alternating sum, col 513 = 0 ----
  if (nt == 0) {
    float tot = nyq + __shfl_xor(nyq, 1);
    if ((tid & 1) == 0) {
      size_t base = (size_t)(m0 + nrow) * NCOLS;
      out[base + 512] = tot;
      out[base + 513] = 0.0f;
    }
  }
#undef STAGE
#undef COMPUTE
#undef NYQ
}

extern "C" void kernel_launch(void* const* d_in, const int* in_sizes, int n_in,
                              void* d_out, int out_size, void* d_ws, size_t ws_size,
                              hipStream_t stream) {
  const float* x  = (const float*)d_in[0];
  const float* rk = (const float*)d_in[1];
  const float* ik = (const float*)d_in[2];
  float* out = (float*)d_out;
  _Float16* wb = (_Float16*)d_ws;  // 512*512*2 B = 512 KB scratch

  prep_w<<<dim3(NPAD), dim3(KDIM), 0, stream>>>(rk, ik, wb);

  dim3 grid(NWG);
  dft_gemm<<<grid, dim3(256), 0, stream>>>(x, wb, out);
}